// Round 16
// baseline (151.590 us; speedup 1.0000x reference)
//
#include <hip/hip_runtime.h>
#include <math.h>

#define NB 10
#define H 512
#define W 512
#define HW (H * W)
#define OH 507
#define OW 507
#define TW 32           // output tile width
#define TH 16           // output tile height
#define HC 39           // hist cols (used)
#define HCP 40          // padded row stride: rows 16B-aligned
#define HR 23           // hist rows
#define IC 41           // xin cols
#define IR 25           // xin rows
#define BD 512          // 8 waves/block, 4 blocks/CU -> 32 waves/CU
#define BSTRIDE (HR * HCP)       // 920 floats per bin plane
#define HISTF (NB * BSTRIDE)     // 9200 floats (= 2300 float4)
#define GX 16           // tiles in x
#define GY 32           // tiles in y
#define NIMG 32
#define NWG (GX * GY * NIMG)     // 16384, divisible by 8

// numpy float32 remainder (np.mod): fmod then sign-fix, each op exact IEEE f32.
__device__ __forceinline__ float f32mod10(float a) {
    float r = fmodf(a, 10.0f);
    if (r < 0.0f) r = __fadd_rn(r, 10.0f);
    return r;
}

__global__ __launch_bounds__(BD, 8)
void hog_fused(const float* __restrict__ x, float* __restrict__ out) {
    __shared__ __align__(16) float hist[HISTF];   // 9200 f
    __shared__ __align__(16) float xin[IR * IC];  // 1025 f -> 40,900 B total

    // ---- XCD-aware bijective swizzle (T1, proven R15) ----
    const int orig = blockIdx.x;
    const int swz  = (orig & 7) * (NWG / 8) + (orig >> 3);
    const int tx   = swz & (GX - 1);
    const int ty   = (swz >> 4) & (GY - 1);
    const int n    = swz >> 9;

    const int tid = threadIdx.x;
    const int ox0 = tx * TW;
    const int oy0 = ty * TH;
    const float* __restrict__ xp = x + (size_t)n * HW;

    // ---- issue input loads FIRST (latency hides under hist zeroing) ----
    const int i1 = tid, i2 = tid + BD;
    int r1 = i1 / IC, c1 = i1 - r1 * IC;
    int r2 = i2 / IC, c2 = i2 - r2 * IC;
    int gy1 = oy0 - 2 + r1, gx1 = ox0 - 2 + c1;
    int gy2 = oy0 - 2 + r2, gx2 = ox0 - 2 + c2;
    const bool v1 = (unsigned)gy1 < H && (unsigned)gx1 < W;
    const bool v2 = (unsigned)gy2 < H && (unsigned)gx2 < W;
    float pv1 = v1 ? xp[gy1 * W + gx1] : 0.0f;
    float pv2 = v2 ? xp[gy2 * W + gx2] : 0.0f;
    float pv3 = 0.0f;
    if (tid == 0 && (unsigned)(oy0 + 22) < H && (unsigned)(ox0 + 38) < W)
        pv3 = xp[(oy0 + 22) * W + (ox0 + 38)];

    // ---- zero hist (2300 float4) ----
    {
        float4* h4 = (float4*)hist;
        for (int i = tid; i < HISTF / 4; i += BD)
            h4[i] = make_float4(0.f, 0.f, 0.f, 0.f);
    }
    // ---- commit tile to LDS ----
    xin[i1] = pv1;
    xin[i2] = pv2;
    if (tid == 0) xin[1024] = pv3;
    __syncthreads();

    // ---- phase S: Sobel + phase + 2-bin scatter (pure stores, R11-proven) ----
    for (int p = tid; p < HR * HC; p += BD) {
        int hr = p / HC, hc = p - (p / HC) * HC;
        int hy = oy0 - 1 + hr, hx = ox0 - 1 + hc;
        if ((unsigned)hy >= H || (unsigned)hx >= W) continue;  // pool pad: zero
        const float* xr = &xin[hr * IC + hc];
        float a00 = xr[0],      a01 = xr[1],          a02 = xr[2];
        float a10 = xr[IC],                           a12 = xr[IC + 2];
        float a20 = xr[2 * IC], a21 = xr[2 * IC + 1], a22 = xr[2 * IC + 2];

        // exact numpy-order f32 conv (no contraction) — proven in round 3
        float gxv = __fadd_rn(a00, -a02);
        gxv = __fadd_rn(gxv, __fmul_rn(2.0f, a10));
        gxv = __fadd_rn(gxv, -__fmul_rn(2.0f, a12));
        gxv = __fadd_rn(gxv, a20);
        gxv = __fadd_rn(gxv, -a22);
        float gyv = __fadd_rn(a00, __fmul_rn(2.0f, a01));
        gyv = __fadd_rn(gyv, a02);
        gyv = __fadd_rn(gyv, -a20);
        gyv = __fadd_rn(gyv, -__fmul_rn(2.0f, a21));
        gyv = __fadd_rn(gyv, -a22);

        float ay_ = fabsf(gxv), ax_ = fabsf(gyv);
        float hi = fmaxf(ax_, ay_), lo = fminf(ax_, ay_);
        if (hi == 0.0f) continue;            // atan2(0,0)=0 -> contributes 0
        float nrm = __builtin_amdgcn_sqrtf(
            __fadd_rn(__fmul_rn(gxv, gxv), __fmul_rn(gyv, gyv)));

        // fast f32 atan2(gxv, gyv) * 10/pi, divide-free
        bool exact = (hi < 1e-30f) || (hi > 1e30f);
        float pint = 0.0f;
        if (!exact) {
            float t  = lo * __builtin_amdgcn_rcpf(hi);
            bool red = t > 0.41421356f;
            float u  = red ? (t - 1.0f) * __builtin_amdgcn_rcpf(t + 1.0f) : t;
            float z  = u * u;
            float pl = ((8.05374449538e-2f * z - 1.38776856032e-1f) * z
                        + 1.99777106478e-1f) * z - 3.33329491539e-1f;
            float a  = fmaf(u * z, pl, u);
            if (red) a += 0.78539816339744831f;
            if (ay_ > ax_) a = 1.57079632679489662f - a;
            if (gyv < 0.0f) a = 3.14159265358979324f - a;
            float ph = (gxv < 0.0f) ? -a : a;
            pint = ph * 3.18309886183790672f;
            if (fabsf(pint - rintf(pint)) < 1e-4f) exact = true;
        }

        float b_v, t_v;
        int ib, it;
        if (exact) {
            // bit-exact round-3 chain (matches np f32 reference)
            float phf = (float)atan2((double)gxv, (double)gyv);
            float pe  = __fmul_rn(__fdiv_rn(phf, (float)3.14159265358979323846), 10.0f);
            float bfv = floorf(pe), tfv = ceilf(pe);
            float fm = f32mod10(pe), bm = f32mod10(bfv), tm = f32mod10(tfv);
            t_v = __fmul_rn(nrm, __fsub_rn(1.0f, __fsub_rn(tm, fm)));
            b_v = __fmul_rn(nrm, __fsub_rn(1.0f, __fsub_rn(fm, bm)));
            ib = (((int)bfv % NB) + NB) % NB;
            it = (((int)tfv % NB) + NB) % NB;
        } else {
            // pint in (-10,10), >=1e-4 from any integer; wrap strips iff ib==9
            float bfv  = floorf(pint);
            float frac = pint - bfv;
            float fm   = (pint < 0.0f) ? pint + 10.0f : pint;
            b_v = nrm * (1.0f - frac);
            int bi = (int)bfv;
            ib = (bi < 0) ? bi + 10 : bi;
            if (ib == 9) { it = 0;      t_v = nrm * (1.0f + fm); }
            else         { it = ib + 1; t_v = nrm * frac; }
        }
        int cell = hr * HCP + hc;
        if (ib == it) {
            hist[ib * BSTRIDE + cell] = __fadd_rn(b_v, t_v);
        } else {
            hist[ib * BSTRIDE + cell] = b_v;
            hist[it * BSTRIDE + cell] = t_v;
        }
    }
    __syncthreads();

    // ---- phase V: vertical 8-row sliding sum, float4 column quads ----
    // unit = (bin, col-quad): 100 units; col[hr*10] = row hr of this quad.
    // Same per-column add/sub order as R15 -> bit-identical sums.
    for (int q = tid; q < NB * (HCP / 4); q += BD) {
        int b = q / 10, c4 = q - (q / 10) * 10;
        float4* col = (float4*)&hist[b * BSTRIDE + c4 * 4];
        float4 s = make_float4(0.f, 0.f, 0.f, 0.f);
        #pragma unroll
        for (int hr = 0; hr < 8; ++hr) {
            float4 v = col[hr * 10];
            s.x += v.x; s.y += v.y; s.z += v.z; s.w += v.w;
        }
        float4 s0 = s;                      // colsum(0) held in reg
        #pragma unroll 4
        for (int i = 1; i < TH; ++i) {
            float4 a = col[(i + 7) * 10];
            float4 d = col[(i - 1) * 10];
            s.x += a.x - d.x; s.y += a.y - d.y;
            s.z += a.z - d.z; s.w += a.w - d.w;
            col[(i - 1) * 10] = s;          // row i-1 dead after this read
        }
        col[22 * 10] = s0;                  // row 22 dead after i=15 read
    }
    __syncthreads();

    // ---- phase H: horizontal sliding 8-sum, 4 b128 reads per unit ----
    float* __restrict__ outn = out + (size_t)n * (NB * OH * OW);
    const float4* h4 = (const float4*)hist;
    for (int u = tid; u < NB * TH * 4; u += BD) {   // 640 units
        int b = u >> 6, i = (u >> 2) & 15, g8 = u & 3;
        int rowf4 = b * (BSTRIDE / 4) + (i == 0 ? 22 : i - 1) * 10 + 2 * g8;
        float4 A = h4[rowf4], B = h4[rowf4 + 1], C = h4[rowf4 + 2], D = h4[rowf4 + 3];
        float o0 = ((A.x + A.y) + (A.z + A.w)) + ((B.x + B.y) + (B.z + B.w));
        float o1 = o0 - A.x + C.x;
        float o2 = o1 - A.y + C.y;
        float o3 = o2 - A.z + C.z;
        float o4 = o3 - A.w + C.w;
        float o5 = o4 - B.x + D.x;
        float o6 = o5 - B.y + D.y;
        float o7 = o6 - B.z + D.z;
        int oy = oy0 + i;
        if (oy < OH) {
            int oxg = ox0 + 8 * g8;
            float* po = outn + (size_t)(b * OH + oy) * OW + oxg;
            if (oxg + 7 < OW) {
                po[0] = o0 * (1.0f / 64.0f); po[1] = o1 * (1.0f / 64.0f);
                po[2] = o2 * (1.0f / 64.0f); po[3] = o3 * (1.0f / 64.0f);
                po[4] = o4 * (1.0f / 64.0f); po[5] = o5 * (1.0f / 64.0f);
                po[6] = o6 * (1.0f / 64.0f); po[7] = o7 * (1.0f / 64.0f);
            } else {
                float ov[8] = {o0, o1, o2, o3, o4, o5, o6, o7};
                #pragma unroll
                for (int j = 0; j < 8; ++j)
                    if (oxg + j < OW) po[j] = ov[j] * (1.0f / 64.0f);
            }
        }
    }
}

extern "C" void kernel_launch(void* const* d_in, const int* in_sizes, int n_in,
                              void* d_out, int out_size, void* d_ws, size_t ws_size,
                              hipStream_t stream) {
    const float* x = (const float*)d_in[0];
    // d_in[1] is the fixed Sobel weight [2,1,3,3]; hard-coded in the kernel.
    float* out = (float*)d_out;
    hog_fused<<<dim3(NWG), dim3(BD), 0, stream>>>(x, out);
}